// Round 1
// baseline (17406.963 us; speedup 1.0000x reference)
//
#include <hip/hip_runtime.h>

// ---------- types / helpers ----------
typedef short short8 __attribute__((ext_vector_type(8)));
typedef __bf16 bf16x8 __attribute__((ext_vector_type(8)));
typedef float f32x4 __attribute__((ext_vector_type(4)));
typedef float f32x4v __attribute__((ext_vector_type(4)));
typedef unsigned short u16x4 __attribute__((ext_vector_type(4)));

__device__ __forceinline__ unsigned short f2b(float f) {
  unsigned x = __builtin_bit_cast(unsigned, f);
  x = x + 0x7fffu + ((x >> 16) & 1u);   // RNE (finite inputs)
  return (unsigned short)(x >> 16);
}
__device__ __forceinline__ float b2f(unsigned short u) {
  unsigned x = ((unsigned)u) << 16;
  return __builtin_bit_cast(float, x);
}
__device__ __forceinline__ f32x4 mfma16(short8 a, short8 b, f32x4 c) {
  return __builtin_amdgcn_mfma_f32_16x16x32_bf16(
      __builtin_bit_cast(bf16x8, a), __builtin_bit_cast(bf16x8, b), c, 0, 0, 0);
}
typedef const __attribute__((address_space(1))) void* gas_p;
typedef __attribute__((address_space(3))) void* las_p;
__device__ __forceinline__ void gload_lds16(const void* g, void* l) {
  __builtin_amdgcn_global_load_lds((gas_p)g, (las_p)l, 16, 0, 0);
}

// ---------- conversion kernels ----------
__global__ __launch_bounds__(256) void k_cvt_bf16(const float* __restrict__ in,
                                                  unsigned short* __restrict__ out,
                                                  int n4) {
  int i = blockIdx.x * 256 + threadIdx.x;
  if (i >= n4) return;
  f32x4v v = *(const f32x4v*)(in + (size_t)i * 4);
  u16x4 o;
  o[0] = f2b(v[0]); o[1] = f2b(v[1]); o[2] = f2b(v[2]); o[3] = f2b(v[3]);
  *(u16x4*)(out + (size_t)i * 4) = o;
}

// out[c][r] = bf16(in[r][c]);  R,C multiples of 32
__global__ __launch_bounds__(256) void k_transpose_bf16(const float* __restrict__ in,
                                                        unsigned short* __restrict__ out,
                                                        int R, int C) {
  __shared__ unsigned short tile[32][33];
  int c0 = blockIdx.x * 32, r0 = blockIdx.y * 32;
  int tx = threadIdx.x & 31, ty = threadIdx.x >> 5;
#pragma unroll
  for (int i = 0; i < 4; i++) {
    int r = ty + i * 8;
    tile[r][tx] = f2b(in[(size_t)(r0 + r) * C + c0 + tx]);
  }
  __syncthreads();
#pragma unroll
  for (int i = 0; i < 4; i++) {
    int rr = ty + i * 8;
    out[(size_t)(c0 + rr) * R + r0 + tx] = tile[tx][rr];
  }
}

__global__ __launch_bounds__(256) void k_zero_u32(unsigned int* __restrict__ p, int n) {
  int i = blockIdx.x * 256 + threadIdx.x;
  if (i < n) p[i] = 0u;
}

// ---------- GEMM1: drive = silu(u)*silu(v)+w, feats = x@W_in + b_in ----------
// A = xb [16384][1024] bf16, B = WinT [3072][1024] bf16 (pre-transposed)
// block tile: 128 rows x 64 feature-cols, 3 accumulator sets (u,v,w). 256 thr.
__global__ __launch_bounds__(256) void k_gemm_drive(const unsigned short* __restrict__ xb,
                                                    const unsigned short* __restrict__ WinT,
                                                    const float* __restrict__ b_in,
                                                    unsigned short* __restrict__ drive) {
  __shared__ unsigned short At[128 * 32];
  __shared__ unsigned short Bt[3][64 * 32];
  const int tid = threadIdx.x;
  const int w = tid >> 6, l = tid & 63;
  const int wm = w >> 1, wn = w & 1;
  const int lr = l & 15, lk = (l >> 4) * 8;
  const int m0 = blockIdx.x * 128;
  const int j0 = blockIdx.y * 64;
  f32x4 acc[3][4][2];
#pragma unroll
  for (int s = 0; s < 3; s++)
#pragma unroll
    for (int mi = 0; mi < 4; mi++)
#pragma unroll
      for (int ni = 0; ni < 2; ni++)
#pragma unroll
        for (int e = 0; e < 4; e++) acc[s][mi][ni][e] = 0.f;

  const int sr = tid >> 2;            // staging row 0..63
  const int skb = (tid & 3) * 8;      // staging k sub-block (shorts)
  for (int kt = 0; kt < 32; kt++) {
    const int k0 = kt * 32;
    gload_lds16(xb + (size_t)(m0 + sr) * 1024 + k0 + skb, &At[w * 512]);
    gload_lds16(xb + (size_t)(m0 + 64 + sr) * 1024 + k0 + skb, &At[2048 + w * 512]);
#pragma unroll
    for (int s = 0; s < 3; s++)
      gload_lds16(WinT + (size_t)(s * 1024 + j0 + sr) * 1024 + k0 + skb, &Bt[s][w * 512]);
    __syncthreads();
    short8 Af[4], Bf[3][2];
#pragma unroll
    for (int mi = 0; mi < 4; mi++)
      Af[mi] = *(const short8*)&At[(wm * 64 + mi * 16 + lr) * 32 + lk];
#pragma unroll
    for (int s = 0; s < 3; s++)
#pragma unroll
      for (int ni = 0; ni < 2; ni++)
        Bf[s][ni] = *(const short8*)&Bt[s][(wn * 32 + ni * 16 + lr) * 32 + lk];
#pragma unroll
    for (int s = 0; s < 3; s++)
#pragma unroll
      for (int mi = 0; mi < 4; mi++)
#pragma unroll
        for (int ni = 0; ni < 2; ni++)
          acc[s][mi][ni] = mfma16(Af[mi], Bf[s][ni], acc[s][mi][ni]);
    __syncthreads();
  }
#pragma unroll
  for (int ni = 0; ni < 2; ni++) {
    const int c = j0 + wn * 32 + ni * 16 + lr;
    const float bu = b_in[c], bv = b_in[1024 + c], bw = b_in[2048 + c];
#pragma unroll
    for (int mi = 0; mi < 4; mi++) {
      const int r0 = m0 + wm * 64 + mi * 16 + (l >> 4) * 4;
#pragma unroll
      for (int e = 0; e < 4; e++) {
        float u = acc[0][mi][ni][e] + bu;
        float v = acc[1][mi][ni][e] + bv;
        float wv = acc[2][mi][ni][e] + bw;
        float su = u / (1.f + __expf(-u));
        float sv = v / (1.f + __expf(-v));
        drive[(size_t)(r0 + e) * 1024 + c] = f2b(su * sv + wv);
      }
    }
  }
}

// ---------- persistent scan kernel ----------
// 32 WGs x 384 threads (6 waves). WG g owns features [32g,32g+32) for all 8 batches.
// Wave w: mat = w>>1 (0=gv,1=gt,2=rec), 16 cols each; weights live in 32 bf16 B-frags
// (128 VGPRs). Per step: spin on flags -> acquire fence -> A-frags from global h
// double buffer -> 32 MFMA -> LDS -> finisher (gate math) -> stores -> release flag.
#define SCAN_PF 16
__global__ __launch_bounds__(384, 1) void k_scan(const unsigned short* __restrict__ WgT,
                                                 const unsigned short* __restrict__ WrT,
                                                 const float* __restrict__ b_gate,
                                                 const float* __restrict__ b_rec,
                                                 const unsigned short* __restrict__ drive,
                                                 unsigned short* __restrict__ hbuf,
                                                 unsigned short* __restrict__ hs,
                                                 float* __restrict__ final_h,
                                                 unsigned int* __restrict__ flags) {
  const int g = blockIdx.x;          // 0..31
  const int tid = threadIdx.x;       // 0..383
  const int w = tid >> 6, l = tid & 63;
  const int mat = w >> 1, j = w & 1;
  const unsigned short* WT = (mat == 2) ? WrT : WgT;
  const int rowbase = ((mat == 1) ? 1024 : 0) + 32 * g + 16 * j;
  const int brow = rowbase + (l & 15);
  const int ko = (l >> 4) * 8;

  short8 Bfr[32];
#pragma unroll
  for (int ks = 0; ks < 32; ks++)
    Bfr[ks] = *(const short8*)&WT[(size_t)brow * 1024 + ks * 32 + ko];

  __shared__ float buf[2][8][96];

  const int fb = tid >> 5, fl = tid & 31;  // finisher (batch, feature) for tid<256
  const int fcol = 32 * g + fl;
  const bool isfin = tid < 256;
  float bgv = 0.f, bgt = 0.f, brc = 0.f;
  if (isfin) { bgv = b_gate[fcol]; bgt = b_gate[1024 + fcol]; brc = b_rec[fcol]; }

  const int ab = l & 15;
  const bool av = ab < 8;
  const int abase = ab * 1024 + ko;

  for (int t = 0; t < 2048; t++) {
    // prefetch drive (independent of h -> hides global latency under the spin)
    unsigned short dpf = 0;
    if (isfin) dpf = drive[(size_t)(fb * 2048 + t) * 1024 + fcol];

    if (t > 0) {  // wait until h_t fully published by all 32 WGs
      const unsigned int* fp = flags + (size_t)t * 32;
      for (;;) {
        unsigned int v = 1u;
        if (l < 32)
          v = __hip_atomic_load((unsigned int*)(fp + l), __ATOMIC_RELAXED,
                                __HIP_MEMORY_SCOPE_AGENT);
        if (__all(v != 0u)) break;
        __builtin_amdgcn_s_sleep(2);
      }
      __threadfence();  // acquire: invalidate L1/L2 so h loads are fresh
    }

    const unsigned short* hb = hbuf + (t & 1) * 8192;
    f32x4 acc;
#pragma unroll
    for (int e = 0; e < 4; e++) acc[e] = 0.f;
    short8 Afr[32];
#pragma unroll
    for (int ks = 0; ks < SCAN_PF; ks++) {
      short8 a;
#pragma unroll
      for (int e = 0; e < 8; e++) a[e] = 0;
      if (av) a = *(const short8*)&hb[abase + ks * 32];
      Afr[ks] = a;
    }
#pragma unroll
    for (int ks = 0; ks < 32; ks++) {
      if (ks + SCAN_PF < 32) {
        short8 a;
#pragma unroll
        for (int e = 0; e < 8; e++) a[e] = 0;
        if (av) a = *(const short8*)&hb[abase + (ks + SCAN_PF) * 32];
        Afr[ks + SCAN_PF] = a;
      }
      acc = mfma16(Afr[ks], Bfr[ks], acc);
    }

    const int p = t & 1;
    if (l < 32) {  // D rows 0..7 = batches live in lanes 0..31
      const int b0 = (l >> 4) * 4;
      const int cw = w * 16 + (l & 15);
#pragma unroll
      for (int e = 0; e < 4; e++) buf[p][b0 + e][cw] = acc[e];
    }
    __syncthreads();
    if (isfin) {
      const float gv = buf[p][fb][fl] + bgv;
      const float gt = buf[p][fb][32 + fl] + bgt;
      const float rc = buf[p][fb][64 + fl] + brc;
      const float sgv = 1.f / (1.f + __expf(-gv));
      const float sgt = 1.f / (1.f + __expf(-gt));
      const float gate = sgv * gt * sgt;  // sigmoid(gv) * silu(gt)
      const float nh = gate * rc + (1.f - gate) * b2f(dpf);
      const unsigned short nhb = f2b(nh);
      hbuf[(p ^ 1) * 8192 + fb * 1024 + fcol] = nhb;
      hs[(size_t)(fb * 2048 + t) * 1024 + fcol] = nhb;
      if (t == 2047) final_h[fb * 1024 + fcol] = nh;
    }
    __syncthreads();  // all stores issued (vmcnt drained at barrier)
    if (t < 2047 && tid == 0) {
      __threadfence();  // release: write back our XCD L2 (covers all WG stores)
      __hip_atomic_store(flags + (size_t)(t + 1) * 32 + g, 1u, __ATOMIC_RELAXED,
                         __HIP_MEMORY_SCOPE_AGENT);
    }
  }
}

// ---------- GEMM3: out = hs @ W_out + b_out ----------
__global__ __launch_bounds__(256) void k_gemm_out(const unsigned short* __restrict__ hs,
                                                  const unsigned short* __restrict__ WoT,
                                                  const float* __restrict__ b_out,
                                                  float* __restrict__ out) {
  __shared__ unsigned short At[128 * 32];
  __shared__ unsigned short Bt[128 * 32];
  const int tid = threadIdx.x;
  const int w = tid >> 6, l = tid & 63;
  const int wm = w >> 1, wn = w & 1;
  const int lr = l & 15, lk = (l >> 4) * 8;
  const int m0 = blockIdx.x * 128;
  const int n0 = blockIdx.y * 128;
  f32x4 acc[4][4];
#pragma unroll
  for (int mi = 0; mi < 4; mi++)
#pragma unroll
    for (int ni = 0; ni < 4; ni++)
#pragma unroll
      for (int e = 0; e < 4; e++) acc[mi][ni][e] = 0.f;

  const int sr = tid >> 2;
  const int skb = (tid & 3) * 8;
  for (int kt = 0; kt < 32; kt++) {
    const int k0 = kt * 32;
    gload_lds16(hs + (size_t)(m0 + sr) * 1024 + k0 + skb, &At[w * 512]);
    gload_lds16(hs + (size_t)(m0 + 64 + sr) * 1024 + k0 + skb, &At[2048 + w * 512]);
    gload_lds16(WoT + (size_t)(n0 + sr) * 1024 + k0 + skb, &Bt[w * 512]);
    gload_lds16(WoT + (size_t)(n0 + 64 + sr) * 1024 + k0 + skb, &Bt[2048 + w * 512]);
    __syncthreads();
    short8 Af[4], Bf[4];
#pragma unroll
    for (int mi = 0; mi < 4; mi++)
      Af[mi] = *(const short8*)&At[(wm * 64 + mi * 16 + lr) * 32 + lk];
#pragma unroll
    for (int ni = 0; ni < 4; ni++)
      Bf[ni] = *(const short8*)&Bt[(wn * 64 + ni * 16 + lr) * 32 + lk];
#pragma unroll
    for (int mi = 0; mi < 4; mi++)
#pragma unroll
      for (int ni = 0; ni < 4; ni++)
        acc[mi][ni] = mfma16(Af[mi], Bf[ni], acc[mi][ni]);
    __syncthreads();
  }
#pragma unroll
  for (int ni = 0; ni < 4; ni++) {
    const int c = n0 + wn * 64 + ni * 16 + lr;
    const float bo = b_out[c];
#pragma unroll
    for (int mi = 0; mi < 4; mi++) {
      const int r0 = m0 + wm * 64 + mi * 16 + (l >> 4) * 4;
#pragma unroll
      for (int e = 0; e < 4; e++)
        out[(size_t)(r0 + e) * 1024 + c] = acc[mi][ni][e] + bo;
    }
  }
}

// ---------- launch ----------
extern "C" void kernel_launch(void* const* d_in, const int* in_sizes, int n_in,
                              void* d_out, int out_size, void* d_ws, size_t ws_size,
                              hipStream_t stream) {
  const float* x      = (const float*)d_in[0];
  const float* h0     = (const float*)d_in[1];
  const float* W_in   = (const float*)d_in[2];
  const float* b_in   = (const float*)d_in[3];
  const float* W_gate = (const float*)d_in[4];
  const float* b_gate = (const float*)d_in[5];
  const float* W_rec  = (const float*)d_in[6];
  const float* b_rec  = (const float*)d_in[7];
  const float* W_out  = (const float*)d_in[8];
  const float* b_out  = (const float*)d_in[9];
  float* outp = (float*)d_out;

  size_t off = 0;
  auto alloc = [&](size_t bytes) {
    void* p = (char*)d_ws + off;
    off += (bytes + 255) & ~(size_t)255;
    return p;
  };
  unsigned short* xb    = (unsigned short*)alloc((size_t)16777216 * 2);
  unsigned short* WinT  = (unsigned short*)alloc((size_t)3072 * 1024 * 2);
  unsigned short* WgT   = (unsigned short*)alloc((size_t)2048 * 1024 * 2);
  unsigned short* WrT   = (unsigned short*)alloc((size_t)1024 * 1024 * 2);
  unsigned short* WoT   = (unsigned short*)alloc((size_t)1024 * 1024 * 2);
  unsigned short* drive = (unsigned short*)alloc((size_t)16777216 * 2);
  unsigned short* hs    = (unsigned short*)alloc((size_t)16777216 * 2);
  unsigned short* hbuf  = (unsigned short*)alloc((size_t)2 * 8192 * 2);
  unsigned int*   flags = (unsigned int*)alloc((size_t)2049 * 32 * 4);

  // conversions / init
  k_cvt_bf16<<<16384, 256, 0, stream>>>(x, xb, 4194304);
  k_transpose_bf16<<<dim3(96, 32), 256, 0, stream>>>(W_in, WinT, 1024, 3072);
  k_transpose_bf16<<<dim3(64, 32), 256, 0, stream>>>(W_gate, WgT, 1024, 2048);
  k_transpose_bf16<<<dim3(32, 32), 256, 0, stream>>>(W_rec, WrT, 1024, 1024);
  k_transpose_bf16<<<dim3(32, 32), 256, 0, stream>>>(W_out, WoT, 1024, 1024);
  k_cvt_bf16<<<8, 256, 0, stream>>>(h0, hbuf, 2048);          // h_0 -> hbuf[0]
  k_zero_u32<<<257, 256, 0, stream>>>(flags, 2049 * 32);      // reset sync flags

  // drive = silu(u)*silu(v)+w
  k_gemm_drive<<<dim3(128, 16), 256, 0, stream>>>(xb, WinT, b_in, drive);
  // sequential recurrence (persistent kernel, 32 co-resident WGs)
  k_scan<<<32, 384, 0, stream>>>(WgT, WrT, b_gate, b_rec, drive, hbuf, hs,
                                 outp + 16777216, flags);
  // out = hs @ W_out + b_out
  k_gemm_out<<<dim3(128, 8), 256, 0, stream>>>(hs, WoT, b_out, outp);
}

// Round 2
// 8568.719 us; speedup vs baseline: 2.0315x; 2.0315x over previous
//
#include <hip/hip_runtime.h>

// ---------- types / helpers ----------
typedef short short8 __attribute__((ext_vector_type(8)));
typedef __bf16 bf16x8 __attribute__((ext_vector_type(8)));
typedef float f32x4 __attribute__((ext_vector_type(4)));
typedef float f32x4v __attribute__((ext_vector_type(4)));
typedef unsigned short u16x4 __attribute__((ext_vector_type(4)));
typedef unsigned long long u64;

__device__ __forceinline__ unsigned short f2b(float f) {
  unsigned x = __builtin_bit_cast(unsigned, f);
  x = x + 0x7fffu + ((x >> 16) & 1u);   // RNE (finite inputs)
  return (unsigned short)(x >> 16);
}
__device__ __forceinline__ float b2f(unsigned short u) {
  unsigned x = ((unsigned)u) << 16;
  return __builtin_bit_cast(float, x);
}
__device__ __forceinline__ f32x4 mfma16(short8 a, short8 b, f32x4 c) {
  return __builtin_amdgcn_mfma_f32_16x16x32_bf16(
      __builtin_bit_cast(bf16x8, a), __builtin_bit_cast(bf16x8, b), c, 0, 0, 0);
}
typedef const __attribute__((address_space(1))) void* gas_p;
typedef __attribute__((address_space(3))) void* las_p;
__device__ __forceinline__ void gload_lds16(const void* g, void* l) {
  __builtin_amdgcn_global_load_lds((gas_p)g, (las_p)l, 16, 0, 0);
}

// ---------- conversion kernels ----------
__global__ __launch_bounds__(256) void k_cvt_bf16(const float* __restrict__ in,
                                                  unsigned short* __restrict__ out,
                                                  int n4) {
  int i = blockIdx.x * 256 + threadIdx.x;
  if (i >= n4) return;
  f32x4v v = *(const f32x4v*)(in + (size_t)i * 4);
  u16x4 o;
  o[0] = f2b(v[0]); o[1] = f2b(v[1]); o[2] = f2b(v[2]); o[3] = f2b(v[3]);
  *(u16x4*)(out + (size_t)i * 4) = o;
}

// hx[0][i] = tag0 | bf16(h0[i]);  hx[1][i] = 0 (tag 0, only ever expected at t=0 on buf0)
__global__ __launch_bounds__(256) void k_init_hx(const float* __restrict__ h0,
                                                 unsigned int* __restrict__ hx) {
  int i = blockIdx.x * 256 + threadIdx.x;
  if (i >= 8192) return;
  hx[i] = (unsigned int)f2b(h0[i]);
  hx[8192 + i] = 0u;
}

// out[c][r] = bf16(in[r][c]);  R,C multiples of 32
__global__ __launch_bounds__(256) void k_transpose_bf16(const float* __restrict__ in,
                                                        unsigned short* __restrict__ out,
                                                        int R, int C) {
  __shared__ unsigned short tile[32][33];
  int c0 = blockIdx.x * 32, r0 = blockIdx.y * 32;
  int tx = threadIdx.x & 31, ty = threadIdx.x >> 5;
#pragma unroll
  for (int i = 0; i < 4; i++) {
    int r = ty + i * 8;
    tile[r][tx] = f2b(in[(size_t)(r0 + r) * C + c0 + tx]);
  }
  __syncthreads();
#pragma unroll
  for (int i = 0; i < 4; i++) {
    int rr = ty + i * 8;
    out[(size_t)(c0 + rr) * R + r0 + tx] = tile[tx][rr];
  }
}

// ---------- GEMM1: drive = silu(u)*silu(v)+w, feats = x@W_in + b_in ----------
__global__ __launch_bounds__(256) void k_gemm_drive(const unsigned short* __restrict__ xb,
                                                    const unsigned short* __restrict__ WinT,
                                                    const float* __restrict__ b_in,
                                                    unsigned short* __restrict__ drive) {
  __shared__ unsigned short At[128 * 32];
  __shared__ unsigned short Bt[3][64 * 32];
  const int tid = threadIdx.x;
  const int w = tid >> 6, l = tid & 63;
  const int wm = w >> 1, wn = w & 1;
  const int lr = l & 15, lk = (l >> 4) * 8;
  const int m0 = blockIdx.x * 128;
  const int j0 = blockIdx.y * 64;
  f32x4 acc[3][4][2];
#pragma unroll
  for (int s = 0; s < 3; s++)
#pragma unroll
    for (int mi = 0; mi < 4; mi++)
#pragma unroll
      for (int ni = 0; ni < 2; ni++)
#pragma unroll
        for (int e = 0; e < 4; e++) acc[s][mi][ni][e] = 0.f;

  const int sr = tid >> 2;
  const int skb = (tid & 3) * 8;
  for (int kt = 0; kt < 32; kt++) {
    const int k0 = kt * 32;
    gload_lds16(xb + (size_t)(m0 + sr) * 1024 + k0 + skb, &At[w * 512]);
    gload_lds16(xb + (size_t)(m0 + 64 + sr) * 1024 + k0 + skb, &At[2048 + w * 512]);
#pragma unroll
    for (int s = 0; s < 3; s++)
      gload_lds16(WinT + (size_t)(s * 1024 + j0 + sr) * 1024 + k0 + skb, &Bt[s][w * 512]);
    __syncthreads();
    short8 Af[4], Bf[3][2];
#pragma unroll
    for (int mi = 0; mi < 4; mi++)
      Af[mi] = *(const short8*)&At[(wm * 64 + mi * 16 + lr) * 32 + lk];
#pragma unroll
    for (int s = 0; s < 3; s++)
#pragma unroll
      for (int ni = 0; ni < 2; ni++)
        Bf[s][ni] = *(const short8*)&Bt[s][(wn * 32 + ni * 16 + lr) * 32 + lk];
#pragma unroll
    for (int s = 0; s < 3; s++)
#pragma unroll
      for (int mi = 0; mi < 4; mi++)
#pragma unroll
        for (int ni = 0; ni < 2; ni++)
          acc[s][mi][ni] = mfma16(Af[mi], Bf[s][ni], acc[s][mi][ni]);
    __syncthreads();
  }
#pragma unroll
  for (int ni = 0; ni < 2; ni++) {
    const int c = j0 + wn * 32 + ni * 16 + lr;
    const float bu = b_in[c], bv = b_in[1024 + c], bw = b_in[2048 + c];
#pragma unroll
    for (int mi = 0; mi < 4; mi++) {
      const int r0 = m0 + wm * 64 + mi * 16 + (l >> 4) * 4;
#pragma unroll
      for (int e = 0; e < 4; e++) {
        float u = acc[0][mi][ni][e] + bu;
        float v = acc[1][mi][ni][e] + bv;
        float wv = acc[2][mi][ni][e] + bw;
        float su = u / (1.f + __expf(-u));
        float sv = v / (1.f + __expf(-v));
        drive[(size_t)(r0 + e) * 1024 + c] = f2b(su * sv + wv);
      }
    }
  }
}

// ---------- persistent scan kernel (one-hop tagged exchange) ----------
// 32 WGs x 384 threads. WG g owns output features [32g,32g+32) for all 8 batches.
// h exchange: hx[2][8][1024] u32, each word = (tag<<16)|bf16; tag(h_t) = t.
// Relaxed agent-scope atomics (per-access sc0/sc1, NO cache-wide fences).
// Per step: [tid<256: poll-load h_t, validate tags, pack->LDS swizzled tile]
//           bar [6 waves: 32 MFMA from LDS, acc->buf] bar [tid<256: gate math,
//           tagged store h_{t+1}, hs store].
__global__ __launch_bounds__(384, 1) void k_scan(const unsigned short* __restrict__ WgT,
                                                 const unsigned short* __restrict__ WrT,
                                                 const float* __restrict__ b_gate,
                                                 const float* __restrict__ b_rec,
                                                 const unsigned short* __restrict__ drive,
                                                 unsigned int* __restrict__ hx,
                                                 unsigned short* __restrict__ hs,
                                                 float* __restrict__ final_h) {
  const int g = blockIdx.x;          // 0..31
  const int tid = threadIdx.x;       // 0..383
  const int w = tid >> 6, l = tid & 63;
  const int mat = w >> 1, j = w & 1;
  const unsigned short* WT = (mat == 2) ? WrT : WgT;
  const int rowbase = ((mat == 1) ? 1024 : 0) + 32 * g + 16 * j;
  const int brow = rowbase + (l & 15);
  const int ko = (l >> 4) * 8;

  // recurrence weights resident in registers for all 2048 steps
  short8 Bfr[32];
#pragma unroll
  for (int ks = 0; ks < 32; ks++)
    Bfr[ks] = *(const short8*)&WT[(size_t)brow * 1024 + ks * 32 + ko];

  // LDS: double-buffered swizzled h tile + MFMA->finisher exchange
  __shared__ unsigned short tileA[2][8][1024];
  __shared__ float buf[2][8][96];

  const int fb = tid >> 5, fl = tid & 31;   // loader/finisher (batch, lane-feat)
  const int fcol = 32 * g + fl;
  const bool isfin = tid < 256;
  float bgv = 0.f, bgt = 0.f, brc = 0.f;
  if (isfin) { bgv = b_gate[fcol]; bgt = b_gate[1024 + fcol]; brc = b_rec[fcol]; }
  const int lf = fl * 2;                    // loader base feature (stride-64 slots)

  const int ab = l & 15;
  const bool av = ab < 8;

  for (int t = 0; t < 2048; t++) {
    const int p = t & 1;
    unsigned short dpf = 0;
    if (isfin) {
      dpf = drive[(size_t)(fb * 2048 + t) * 1024 + fcol];  // plain cached load
      // ---- poll-load h_t (tags must equal t), pack to LDS ----
      const unsigned tg = (unsigned)t;
      u64* hb = (u64*)(hx + (size_t)p * 8192 + fb * 1024 + lf);
      unsigned pend = 0xffffu;
      u64 v[16];
      char* ldsrow = (char*)&tileA[p][fb][0];
      const unsigned swz = (unsigned)((fb & 7) << 4);
      while (pend) {
#pragma unroll
        for (int q = 0; q < 16; q++)
          if ((pend >> q) & 1)
            v[q] = __hip_atomic_load(hb + q * 32, __ATOMIC_RELAXED,
                                     __HIP_MEMORY_SCOPE_AGENT);
        unsigned np = 0;
#pragma unroll
        for (int q = 0; q < 16; q++)
          if ((pend >> q) & 1) {
            unsigned lo = (unsigned)v[q], hi = (unsigned)(v[q] >> 32);
            if (((lo >> 16) == tg) & ((hi >> 16) == tg)) {
              unsigned pk = __builtin_amdgcn_perm(hi, lo, 0x05040100u);
              *(unsigned*)(ldsrow + (((unsigned)(lf * 2 + q * 128)) ^ swz)) = pk;
            } else np |= 1u << q;
          }
        pend = np;
      }
    }
    __syncthreads();

    // ---- MFMA phase: acc[b, col] += sum_ks h[b, ks-slice] * W[col, ks-slice] ----
    f32x4 acc;
#pragma unroll
    for (int e = 0; e < 4; e++) acc[e] = 0.f;
    {
      char* base = (char*)&tileA[p][0][0];
#pragma unroll
      for (int ks = 0; ks < 32; ks++) {
        short8 a;
#pragma unroll
        for (int e = 0; e < 8; e++) a[e] = 0;
        if (av)
          a = *(const short8*)(base + ab * 2048 +
                               (((unsigned)(ks * 64 + ko * 2)) ^ (unsigned)(ab << 4)));
        acc = mfma16(a, Bfr[ks], acc);
      }
    }
    if (l < 32) {
      const int b0 = (l >> 4) * 4;
      const int cw = w * 16 + (l & 15);
#pragma unroll
      for (int e = 0; e < 4; e++) buf[p][b0 + e][cw] = acc[e];
    }
    __syncthreads();

    // ---- finisher: gate math + tagged publish of h_{t+1} ----
    if (isfin) {
      const float gv = buf[p][fb][fl] + bgv;
      const float gt = buf[p][fb][32 + fl] + bgt;
      const float rc = buf[p][fb][64 + fl] + brc;
      const float sgv = 1.f / (1.f + __expf(-gv));
      const float sgt = 1.f / (1.f + __expf(-gt));
      const float gate = sgv * gt * sgt;  // sigmoid(gv) * silu(gt)
      const float nh = gate * rc + (1.f - gate) * b2f(dpf);
      const unsigned short nhb = f2b(nh);
      const unsigned pkv = (((unsigned)(t + 1)) << 16) | (unsigned)nhb;
      __hip_atomic_store(hx + (size_t)(p ^ 1) * 8192 + fb * 1024 + fcol, pkv,
                         __ATOMIC_RELAXED, __HIP_MEMORY_SCOPE_AGENT);
      hs[(size_t)(fb * 2048 + t) * 1024 + fcol] = nhb;
      if (t == 2047) final_h[fb * 1024 + fcol] = nh;
    }
  }
}

// ---------- GEMM3: out = hs @ W_out + b_out ----------
__global__ __launch_bounds__(256) void k_gemm_out(const unsigned short* __restrict__ hs,
                                                  const unsigned short* __restrict__ WoT,
                                                  const float* __restrict__ b_out,
                                                  float* __restrict__ out) {
  __shared__ unsigned short At[128 * 32];
  __shared__ unsigned short Bt[128 * 32];
  const int tid = threadIdx.x;
  const int w = tid >> 6, l = tid & 63;
  const int wm = w >> 1, wn = w & 1;
  const int lr = l & 15, lk = (l >> 4) * 8;
  const int m0 = blockIdx.x * 128;
  const int n0 = blockIdx.y * 128;
  f32x4 acc[4][4];
#pragma unroll
  for (int mi = 0; mi < 4; mi++)
#pragma unroll
    for (int ni = 0; ni < 4; ni++)
#pragma unroll
      for (int e = 0; e < 4; e++) acc[mi][ni][e] = 0.f;

  const int sr = tid >> 2;
  const int skb = (tid & 3) * 8;
  for (int kt = 0; kt < 32; kt++) {
    const int k0 = kt * 32;
    gload_lds16(hs + (size_t)(m0 + sr) * 1024 + k0 + skb, &At[w * 512]);
    gload_lds16(hs + (size_t)(m0 + 64 + sr) * 1024 + k0 + skb, &At[2048 + w * 512]);
    gload_lds16(WoT + (size_t)(n0 + sr) * 1024 + k0 + skb, &Bt[w * 512]);
    gload_lds16(WoT + (size_t)(n0 + 64 + sr) * 1024 + k0 + skb, &Bt[2048 + w * 512]);
    __syncthreads();
    short8 Af[4], Bf[4];
#pragma unroll
    for (int mi = 0; mi < 4; mi++)
      Af[mi] = *(const short8*)&At[(wm * 64 + mi * 16 + lr) * 32 + lk];
#pragma unroll
    for (int ni = 0; ni < 4; ni++)
      Bf[ni] = *(const short8*)&Bt[(wn * 64 + ni * 16 + lr) * 32 + lk];
#pragma unroll
    for (int mi = 0; mi < 4; mi++)
#pragma unroll
      for (int ni = 0; ni < 4; ni++)
        acc[mi][ni] = mfma16(Af[mi], Bf[ni], acc[mi][ni]);
    __syncthreads();
  }
#pragma unroll
  for (int ni = 0; ni < 4; ni++) {
    const int c = n0 + wn * 64 + ni * 16 + lr;
    const float bo = b_out[c];
#pragma unroll
    for (int mi = 0; mi < 4; mi++) {
      const int r0 = m0 + wm * 64 + mi * 16 + (l >> 4) * 4;
#pragma unroll
      for (int e = 0; e < 4; e++)
        out[(size_t)(r0 + e) * 1024 + c] = acc[mi][ni][e] + bo;
    }
  }
}

// ---------- launch ----------
extern "C" void kernel_launch(void* const* d_in, const int* in_sizes, int n_in,
                              void* d_out, int out_size, void* d_ws, size_t ws_size,
                              hipStream_t stream) {
  const float* x      = (const float*)d_in[0];
  const float* h0     = (const float*)d_in[1];
  const float* W_in   = (const float*)d_in[2];
  const float* b_in   = (const float*)d_in[3];
  const float* W_gate = (const float*)d_in[4];
  const float* b_gate = (const float*)d_in[5];
  const float* W_rec  = (const float*)d_in[6];
  const float* b_rec  = (const float*)d_in[7];
  const float* W_out  = (const float*)d_in[8];
  const float* b_out  = (const float*)d_in[9];
  float* outp = (float*)d_out;

  size_t off = 0;
  auto alloc = [&](size_t bytes) {
    void* p = (char*)d_ws + off;
    off += (bytes + 255) & ~(size_t)255;
    return p;
  };
  unsigned short* xb    = (unsigned short*)alloc((size_t)16777216 * 2);
  unsigned short* WinT  = (unsigned short*)alloc((size_t)3072 * 1024 * 2);
  unsigned short* WgT   = (unsigned short*)alloc((size_t)2048 * 1024 * 2);
  unsigned short* WrT   = (unsigned short*)alloc((size_t)1024 * 1024 * 2);
  unsigned short* WoT   = (unsigned short*)alloc((size_t)1024 * 1024 * 2);
  unsigned short* drive = (unsigned short*)alloc((size_t)16777216 * 2);
  unsigned short* hs    = (unsigned short*)alloc((size_t)16777216 * 2);
  unsigned int*   hx    = (unsigned int*)alloc((size_t)2 * 8192 * 4);

  // conversions / init
  k_cvt_bf16<<<16384, 256, 0, stream>>>(x, xb, 4194304);
  k_transpose_bf16<<<dim3(96, 32), 256, 0, stream>>>(W_in, WinT, 1024, 3072);
  k_transpose_bf16<<<dim3(64, 32), 256, 0, stream>>>(W_gate, WgT, 1024, 2048);
  k_transpose_bf16<<<dim3(32, 32), 256, 0, stream>>>(W_rec, WrT, 1024, 1024);
  k_transpose_bf16<<<dim3(32, 32), 256, 0, stream>>>(W_out, WoT, 1024, 1024);
  k_init_hx<<<32, 256, 0, stream>>>(h0, hx);

  // drive = silu(u)*silu(v)+w
  k_gemm_drive<<<dim3(128, 16), 256, 0, stream>>>(xb, WinT, b_in, drive);
  // sequential recurrence (persistent kernel, 32 co-resident WGs, fence-free)
  k_scan<<<32, 384, 0, stream>>>(WgT, WrT, b_gate, b_rec, drive, hx, hs,
                                 outp + 16777216);
  // out = hs @ W_out + b_out
  k_gemm_out<<<dim3(128, 8), 256, 0, stream>>>(hs, WoT, b_out, outp);
}

// Round 3
// 7316.551 us; speedup vs baseline: 2.3791x; 1.1711x over previous
//
#include <hip/hip_runtime.h>

// ---------- types / helpers ----------
typedef short short8 __attribute__((ext_vector_type(8)));
typedef __bf16 bf16x8 __attribute__((ext_vector_type(8)));
typedef float f32x4 __attribute__((ext_vector_type(4)));
typedef float f32x4v __attribute__((ext_vector_type(4)));
typedef unsigned short u16x4 __attribute__((ext_vector_type(4)));
typedef unsigned long long u64;

__device__ __forceinline__ unsigned short f2b(float f) {
  unsigned x = __builtin_bit_cast(unsigned, f);
  x = x + 0x7fffu + ((x >> 16) & 1u);   // RNE (finite inputs)
  return (unsigned short)(x >> 16);
}
__device__ __forceinline__ float b2f(unsigned short u) {
  unsigned x = ((unsigned)u) << 16;
  return __builtin_bit_cast(float, x);
}
__device__ __forceinline__ f32x4 mfma16(short8 a, short8 b, f32x4 c) {
  return __builtin_amdgcn_mfma_f32_16x16x32_bf16(
      __builtin_bit_cast(bf16x8, a), __builtin_bit_cast(bf16x8, b), c, 0, 0, 0);
}
typedef const __attribute__((address_space(1))) void* gas_p;
typedef __attribute__((address_space(3))) void* las_p;
__device__ __forceinline__ void gload_lds16(const void* g, void* l) {
  __builtin_amdgcn_global_load_lds((gas_p)g, (las_p)l, 16, 0, 0);
}

// ---------- conversion kernels ----------
__global__ __launch_bounds__(256) void k_cvt_bf16(const float* __restrict__ in,
                                                  unsigned short* __restrict__ out,
                                                  int n4) {
  int i = blockIdx.x * 256 + threadIdx.x;
  if (i >= n4) return;
  f32x4v v = *(const f32x4v*)(in + (size_t)i * 4);
  u16x4 o;
  o[0] = f2b(v[0]); o[1] = f2b(v[1]); o[2] = f2b(v[2]); o[3] = f2b(v[3]);
  *(u16x4*)(out + (size_t)i * 4) = o;
}

// hx[0][i] = tag0 | bf16(h0[i]);  hx[1][i] = 0
__global__ __launch_bounds__(256) void k_init_hx(const float* __restrict__ h0,
                                                 unsigned int* __restrict__ hx) {
  int i = blockIdx.x * 256 + threadIdx.x;
  if (i >= 8192) return;
  hx[i] = (unsigned int)f2b(h0[i]);
  hx[8192 + i] = 0u;
}

// out[c][r] = bf16(in[r][c]);  R,C multiples of 32
__global__ __launch_bounds__(256) void k_transpose_bf16(const float* __restrict__ in,
                                                        unsigned short* __restrict__ out,
                                                        int R, int C) {
  __shared__ unsigned short tile[32][33];
  int c0 = blockIdx.x * 32, r0 = blockIdx.y * 32;
  int tx = threadIdx.x & 31, ty = threadIdx.x >> 5;
#pragma unroll
  for (int i = 0; i < 4; i++) {
    int r = ty + i * 8;
    tile[r][tx] = f2b(in[(size_t)(r0 + r) * C + c0 + tx]);
  }
  __syncthreads();
#pragma unroll
  for (int i = 0; i < 4; i++) {
    int rr = ty + i * 8;
    out[(size_t)(c0 + rr) * R + r0 + tx] = tile[tx][rr];
  }
}

// ---------- GEMM1: drive = silu(u)*silu(v)+w, feats = x@W_in + b_in ----------
__global__ __launch_bounds__(256) void k_gemm_drive(const unsigned short* __restrict__ xb,
                                                    const unsigned short* __restrict__ WinT,
                                                    const float* __restrict__ b_in,
                                                    unsigned short* __restrict__ drive) {
  __shared__ unsigned short At[128 * 32];
  __shared__ unsigned short Bt[3][64 * 32];
  const int tid = threadIdx.x;
  const int w = tid >> 6, l = tid & 63;
  const int wm = w >> 1, wn = w & 1;
  const int lr = l & 15, lk = (l >> 4) * 8;
  const int m0 = blockIdx.x * 128;
  const int j0 = blockIdx.y * 64;
  f32x4 acc[3][4][2];
#pragma unroll
  for (int s = 0; s < 3; s++)
#pragma unroll
    for (int mi = 0; mi < 4; mi++)
#pragma unroll
      for (int ni = 0; ni < 2; ni++)
#pragma unroll
        for (int e = 0; e < 4; e++) acc[s][mi][ni][e] = 0.f;

  const int sr = tid >> 2;
  const int skb = (tid & 3) * 8;
  for (int kt = 0; kt < 32; kt++) {
    const int k0 = kt * 32;
    gload_lds16(xb + (size_t)(m0 + sr) * 1024 + k0 + skb, &At[w * 512]);
    gload_lds16(xb + (size_t)(m0 + 64 + sr) * 1024 + k0 + skb, &At[2048 + w * 512]);
#pragma unroll
    for (int s = 0; s < 3; s++)
      gload_lds16(WinT + (size_t)(s * 1024 + j0 + sr) * 1024 + k0 + skb, &Bt[s][w * 512]);
    __syncthreads();
    short8 Af[4], Bf[3][2];
#pragma unroll
    for (int mi = 0; mi < 4; mi++)
      Af[mi] = *(const short8*)&At[(wm * 64 + mi * 16 + lr) * 32 + lk];
#pragma unroll
    for (int s = 0; s < 3; s++)
#pragma unroll
      for (int ni = 0; ni < 2; ni++)
        Bf[s][ni] = *(const short8*)&Bt[s][(wn * 32 + ni * 16 + lr) * 32 + lk];
#pragma unroll
    for (int s = 0; s < 3; s++)
#pragma unroll
      for (int mi = 0; mi < 4; mi++)
#pragma unroll
        for (int ni = 0; ni < 2; ni++)
          acc[s][mi][ni] = mfma16(Af[mi], Bf[s][ni], acc[s][mi][ni]);
    __syncthreads();
  }
#pragma unroll
  for (int ni = 0; ni < 2; ni++) {
    const int c = j0 + wn * 32 + ni * 16 + lr;
    const float bu = b_in[c], bv = b_in[1024 + c], bw = b_in[2048 + c];
#pragma unroll
    for (int mi = 0; mi < 4; mi++) {
      const int r0 = m0 + wm * 64 + mi * 16 + (l >> 4) * 4;
#pragma unroll
      for (int e = 0; e < 4; e++) {
        float u = acc[0][mi][ni][e] + bu;
        float v = acc[1][mi][ni][e] + bv;
        float wv = acc[2][mi][ni][e] + bw;
        float su = u / (1.f + __expf(-u));
        float sv = v / (1.f + __expf(-v));
        drive[(size_t)(r0 + e) * 1024 + c] = f2b(su * sv + wv);
      }
    }
  }
}

// ---------- persistent scan kernel v3 ----------
// 64 WGs x 384 threads. WG g owns h-features [16g,16g+16) => 48 weight cols
// (gv,gt,rec x16) staged ONCE into swizzled LDS (98.3KB) - guaranteed resident.
// h exchange: hx[2][8192] u32, word = (tag<<16)|bf16, tag(h_t)=t, relaxed
// agent-scope atomics (L3 one-hop, no fences).
// Roles: waves 2-5 (tid>=128): poll h_t (branchless 16xu64 sweeps) + pack to
// swizzled LDS tile; wave 0-1 (tid<128): gate math + tagged publish.
// All 6 waves: (mat,khalf) MFMA role, 16 MFMAs in 4 indep chains; K-halves
// reduced via LDS buf.
#define SMEM_W 0
#define SMEM_TILE 98304
#define SMEM_BUF 114688
#define SMEM_TOTAL 117760

__global__ __launch_bounds__(384, 1) void k_scan(const unsigned short* __restrict__ WgT,
                                                 const unsigned short* __restrict__ WrT,
                                                 const float* __restrict__ b_gate,
                                                 const float* __restrict__ b_rec,
                                                 const unsigned short* __restrict__ drive,
                                                 unsigned int* __restrict__ hx,
                                                 unsigned short* __restrict__ hs,
                                                 float* __restrict__ final_h) {
  extern __shared__ char smem[];
  const int g = blockIdx.x;          // 0..63
  const int tid = threadIdx.x;       // 0..383
  const int w = tid >> 6, l = tid & 63;
  const int mat = w >> 1, kh = w & 1;

  // ---- stage weights once: 48 rows x 2048B, XOR-swizzled via global source ----
  for (int it = 0; it < 16; ++it) {
    const int chunk = it * 6 + w;        // 0..95, 1KB each (half a row)
    const int lcol = chunk >> 1;         // 0..47
    const int half = chunk & 1;
    const int m2 = lcol >> 4, ff = lcol & 15;
    const unsigned short* rowp =
        (m2 == 0) ? WgT + (size_t)(g * 16 + ff) * 1024
      : (m2 == 1) ? WgT + (size_t)(1024 + g * 16 + ff) * 1024
                  : WrT + (size_t)(g * 16 + ff) * 1024;
    const unsigned soff =
        ((unsigned)(half * 1024 + l * 16)) ^ ((unsigned)((lcol & 7) << 4));
    gload_lds16((const char*)rowp + soff, smem + SMEM_W + chunk * 1024);
  }

  float* bufp = (float*)(smem + SMEM_BUF);   // [kh][8][48] f32

  // MFMA-role constants
  const int c = l & 15;
  const int ko16 = (l >> 4) * 16;            // k-slice byte offset within 64B
  const char* Wbase = smem + SMEM_W + (size_t)(mat * 16 + c) * 2048;
  const unsigned swzB = (unsigned)((c & 7) << 4);
  const char* Abase = smem + SMEM_TILE + (size_t)c * 2048;
  const unsigned swzA = (unsigned)(c << 4);
  const bool av = c < 8;
  const unsigned kbase = (unsigned)(kh * 1024 + ko16);

  // loader constants (tid in [128,384))
  const bool isld = tid >= 128;
  const int L = tid - 128;                   // 0..255
  const int lb = L >> 5, lc = L & 31;        // batch, feature-chunk
  char* ldsrow = smem + SMEM_TILE + (size_t)lb * 2048;
  const unsigned swzL = (unsigned)((lb & 7) << 4);

  // finisher constants (tid<128)
  const bool isfin = tid < 128;
  const int fb = tid >> 4, ff2 = tid & 15;
  const int fcol = g * 16 + ff2;
  float bgv = 0.f, bgt = 0.f, brc = 0.f;
  if (isfin) { bgv = b_gate[fcol]; bgt = b_gate[1024 + fcol]; brc = b_rec[fcol]; }

  __syncthreads();  // weights staged (vmcnt drained at barrier)

  for (int t = 0; t < 2048; ++t) {
    const int p = t & 1;
    unsigned short dpf = 0;
    if (isfin) dpf = drive[(size_t)(fb * 2048 + t) * 1024 + fcol];

    if (isld) {  // ---- poll h_t (all tags == t), then pack to swizzled tile ----
      const unsigned tg = (unsigned)t;
      const u64* hb = (const u64*)(hx + (size_t)p * 8192) + (lb * 512 + lc);
      u64 v[16];
      bool ok;
      do {
#pragma unroll
        for (int q = 0; q < 16; ++q)
          v[q] = __hip_atomic_load(hb + q * 32, __ATOMIC_RELAXED,
                                   __HIP_MEMORY_SCOPE_AGENT);
        ok = true;
#pragma unroll
        for (int q = 0; q < 16; ++q) {
          unsigned lo = (unsigned)v[q], hi = (unsigned)(v[q] >> 32);
          ok = ok && ((lo >> 16) == tg) && ((hi >> 16) == tg);
        }
      } while (!ok);
#pragma unroll
      for (int q = 0; q < 16; ++q) {
        unsigned lo = (unsigned)v[q], hi = (unsigned)(v[q] >> 32);
        unsigned pk = __builtin_amdgcn_perm(hi, lo, 0x05040100u);
        *(unsigned*)(ldsrow + (((unsigned)(lc * 4 + q * 128)) ^ swzL)) = pk;
      }
    }
    __syncthreads();

    // ---- MFMA: 16 steps, 4 independent chains ----
    f32x4 acc[4];
#pragma unroll
    for (int i = 0; i < 4; ++i)
#pragma unroll
      for (int e = 0; e < 4; ++e) acc[i][e] = 0.f;
#pragma unroll
    for (int ks = 0; ks < 16; ++ks) {
      const unsigned kb = kbase + (unsigned)(ks * 64);
      short8 Bf = *(const short8*)(Wbase + (kb ^ swzB));
      short8 Af;
#pragma unroll
      for (int e = 0; e < 8; ++e) Af[e] = 0;
      if (av) Af = *(const short8*)(Abase + (kb ^ swzA));
      acc[ks & 3] = mfma16(Af, Bf, acc[ks & 3]);
    }
    f32x4 sum;
#pragma unroll
    for (int e = 0; e < 4; ++e)
      sum[e] = (acc[0][e] + acc[1][e]) + (acc[2][e] + acc[3][e]);
    if (l < 32) {
      const int b0 = (l >> 4) * 4;
      const int cc = mat * 16 + (l & 15);
#pragma unroll
      for (int e = 0; e < 4; ++e)
        bufp[kh * 384 + (b0 + e) * 48 + cc] = sum[e];
    }
    __syncthreads();

    // ---- finisher: K-half reduce + gate math + tagged publish ----
    if (isfin) {
      const float gv = bufp[fb * 48 + ff2] + bufp[384 + fb * 48 + ff2] + bgv;
      const float gt = bufp[fb * 48 + 16 + ff2] + bufp[384 + fb * 48 + 16 + ff2] + bgt;
      const float rc = bufp[fb * 48 + 32 + ff2] + bufp[384 + fb * 48 + 32 + ff2] + brc;
      const float sgv = 1.f / (1.f + __expf(-gv));
      const float sgt = 1.f / (1.f + __expf(-gt));
      const float gate = sgv * gt * sgt;  // sigmoid(gv) * silu(gt)
      const float nh = gate * rc + (1.f - gate) * b2f(dpf);
      const unsigned short nhb = f2b(nh);
      __hip_atomic_store(hx + (size_t)(p ^ 1) * 8192 + fb * 1024 + fcol,
                         (((unsigned)(t + 1)) << 16) | (unsigned)nhb,
                         __ATOMIC_RELAXED, __HIP_MEMORY_SCOPE_AGENT);
      hs[(size_t)(fb * 2048 + t) * 1024 + fcol] = nhb;
      if (t == 2047) final_h[fb * 1024 + fcol] = nh;
    }
  }
}

// ---------- GEMM3: out = hs @ W_out + b_out ----------
__global__ __launch_bounds__(256) void k_gemm_out(const unsigned short* __restrict__ hs,
                                                  const unsigned short* __restrict__ WoT,
                                                  const float* __restrict__ b_out,
                                                  float* __restrict__ out) {
  __shared__ unsigned short At[128 * 32];
  __shared__ unsigned short Bt[128 * 32];
  const int tid = threadIdx.x;
  const int w = tid >> 6, l = tid & 63;
  const int wm = w >> 1, wn = w & 1;
  const int lr = l & 15, lk = (l >> 4) * 8;
  const int m0 = blockIdx.x * 128;
  const int n0 = blockIdx.y * 128;
  f32x4 acc[4][4];
#pragma unroll
  for (int mi = 0; mi < 4; mi++)
#pragma unroll
    for (int ni = 0; ni < 4; ni++)
#pragma unroll
      for (int e = 0; e < 4; e++) acc[mi][ni][e] = 0.f;

  const int sr = tid >> 2;
  const int skb = (tid & 3) * 8;
  for (int kt = 0; kt < 32; kt++) {
    const int k0 = kt * 32;
    gload_lds16(hs + (size_t)(m0 + sr) * 1024 + k0 + skb, &At[w * 512]);
    gload_lds16(hs + (size_t)(m0 + 64 + sr) * 1024 + k0 + skb, &At[2048 + w * 512]);
    gload_lds16(WoT + (size_t)(n0 + sr) * 1024 + k0 + skb, &Bt[w * 512]);
    gload_lds16(WoT + (size_t)(n0 + 64 + sr) * 1024 + k0 + skb, &Bt[2048 + w * 512]);
    __syncthreads();
    short8 Af[4], Bf[4];
#pragma unroll
    for (int mi = 0; mi < 4; mi++)
      Af[mi] = *(const short8*)&At[(wm * 64 + mi * 16 + lr) * 32 + lk];
#pragma unroll
    for (int ni = 0; ni < 4; ni++)
      Bf[ni] = *(const short8*)&Bt[(wn * 64 + ni * 16 + lr) * 32 + lk];
#pragma unroll
    for (int mi = 0; mi < 4; mi++)
#pragma unroll
      for (int ni = 0; ni < 4; ni++)
        acc[mi][ni] = mfma16(Af[mi], Bf[ni], acc[mi][ni]);
    __syncthreads();
  }
#pragma unroll
  for (int ni = 0; ni < 4; ni++) {
    const int c = n0 + wn * 64 + ni * 16 + lr;
    const float bo = b_out[c];
#pragma unroll
    for (int mi = 0; mi < 4; mi++) {
      const int r0 = m0 + wm * 64 + mi * 16 + (l >> 4) * 4;
#pragma unroll
      for (int e = 0; e < 4; e++)
        out[(size_t)(r0 + e) * 1024 + c] = acc[mi][ni][e] + bo;
    }
  }
}

// ---------- launch ----------
extern "C" void kernel_launch(void* const* d_in, const int* in_sizes, int n_in,
                              void* d_out, int out_size, void* d_ws, size_t ws_size,
                              hipStream_t stream) {
  const float* x      = (const float*)d_in[0];
  const float* h0     = (const float*)d_in[1];
  const float* W_in   = (const float*)d_in[2];
  const float* b_in   = (const float*)d_in[3];
  const float* W_gate = (const float*)d_in[4];
  const float* b_gate = (const float*)d_in[5];
  const float* W_rec  = (const float*)d_in[6];
  const float* b_rec  = (const float*)d_in[7];
  const float* W_out  = (const float*)d_in[8];
  const float* b_out  = (const float*)d_in[9];
  float* outp = (float*)d_out;

  // allow >64KB dynamic LDS for k_scan (host-side attr, capture-safe)
  (void)hipFuncSetAttribute(reinterpret_cast<const void*>(&k_scan),
                            hipFuncAttributeMaxDynamicSharedMemorySize, SMEM_TOTAL);

  size_t off = 0;
  auto alloc = [&](size_t bytes) {
    void* p = (char*)d_ws + off;
    off += (bytes + 255) & ~(size_t)255;
    return p;
  };
  unsigned short* xb    = (unsigned short*)alloc((size_t)16777216 * 2);
  unsigned short* WinT  = (unsigned short*)alloc((size_t)3072 * 1024 * 2);
  unsigned short* WgT   = (unsigned short*)alloc((size_t)2048 * 1024 * 2);
  unsigned short* WrT   = (unsigned short*)alloc((size_t)1024 * 1024 * 2);
  unsigned short* WoT   = (unsigned short*)alloc((size_t)1024 * 1024 * 2);
  unsigned short* drive = (unsigned short*)alloc((size_t)16777216 * 2);
  unsigned short* hs    = (unsigned short*)alloc((size_t)16777216 * 2);
  unsigned int*   hx    = (unsigned int*)alloc((size_t)2 * 8192 * 4);

  // conversions / init
  k_cvt_bf16<<<16384, 256, 0, stream>>>(x, xb, 4194304);
  k_transpose_bf16<<<dim3(96, 32), 256, 0, stream>>>(W_in, WinT, 1024, 3072);
  k_transpose_bf16<<<dim3(64, 32), 256, 0, stream>>>(W_gate, WgT, 1024, 2048);
  k_transpose_bf16<<<dim3(32, 32), 256, 0, stream>>>(W_rec, WrT, 1024, 1024);
  k_transpose_bf16<<<dim3(32, 32), 256, 0, stream>>>(W_out, WoT, 1024, 1024);
  k_init_hx<<<32, 256, 0, stream>>>(h0, hx);

  // drive = silu(u)*silu(v)+w
  k_gemm_drive<<<dim3(128, 16), 256, 0, stream>>>(xb, WinT, b_in, drive);
  // sequential recurrence (persistent kernel, 64 co-resident WGs, LDS weights)
  k_scan<<<64, 384, SMEM_TOTAL, stream>>>(WgT, WrT, b_gate, b_rec, drive, hx, hs,
                                          outp + 16777216);
  // out = hs @ W_out + b_out
  k_gemm_out<<<dim3(128, 8), 256, 0, stream>>>(hs, WoT, b_out, outp);
}

// Round 4
// 7192.310 us; speedup vs baseline: 2.4202x; 1.0173x over previous
//
#include <hip/hip_runtime.h>

// ---------- types / helpers ----------
typedef short short8 __attribute__((ext_vector_type(8)));
typedef __bf16 bf16x8 __attribute__((ext_vector_type(8)));
typedef float f32x4 __attribute__((ext_vector_type(4)));
typedef float f32x4v __attribute__((ext_vector_type(4)));
typedef unsigned short u16x4 __attribute__((ext_vector_type(4)));
typedef unsigned long long u64;

__device__ __forceinline__ unsigned short f2b(float f) {
  unsigned x = __builtin_bit_cast(unsigned, f);
  x = x + 0x7fffu + ((x >> 16) & 1u);   // RNE (finite inputs)
  return (unsigned short)(x >> 16);
}
__device__ __forceinline__ float b2f(unsigned short u) {
  unsigned x = ((unsigned)u) << 16;
  return __builtin_bit_cast(float, x);
}
__device__ __forceinline__ f32x4 mfma16(short8 a, short8 b, f32x4 c) {
  return __builtin_amdgcn_mfma_f32_16x16x32_bf16(
      __builtin_bit_cast(bf16x8, a), __builtin_bit_cast(bf16x8, b), c, 0, 0, 0);
}
typedef const __attribute__((address_space(1))) void* gas_p;
typedef __attribute__((address_space(3))) void* las_p;
__device__ __forceinline__ void gload_lds16(const void* g, void* l) {
  __builtin_amdgcn_global_load_lds((gas_p)g, (las_p)l, 16, 0, 0);
}

// ---------- conversion kernels ----------
__global__ __launch_bounds__(256) void k_cvt_bf16(const float* __restrict__ in,
                                                  unsigned short* __restrict__ out,
                                                  int n4) {
  int i = blockIdx.x * 256 + threadIdx.x;
  if (i >= n4) return;
  f32x4v v = *(const f32x4v*)(in + (size_t)i * 4);
  u16x4 o;
  o[0] = f2b(v[0]); o[1] = f2b(v[1]); o[2] = f2b(v[2]); o[3] = f2b(v[3]);
  *(u16x4*)(out + (size_t)i * 4) = o;
}

// hx[0][i] = tag0 | bf16(h0[i]);  hx[1][i] = 0
__global__ __launch_bounds__(256) void k_init_hx(const float* __restrict__ h0,
                                                 unsigned int* __restrict__ hx) {
  int i = blockIdx.x * 256 + threadIdx.x;
  if (i >= 8192) return;
  hx[i] = (unsigned int)f2b(h0[i]);
  hx[8192 + i] = 0u;
}

// out[c][r] = bf16(in[r][c]);  R,C multiples of 32
__global__ __launch_bounds__(256) void k_transpose_bf16(const float* __restrict__ in,
                                                        unsigned short* __restrict__ out,
                                                        int R, int C) {
  __shared__ unsigned short tile[32][33];
  int c0 = blockIdx.x * 32, r0 = blockIdx.y * 32;
  int tx = threadIdx.x & 31, ty = threadIdx.x >> 5;
#pragma unroll
  for (int i = 0; i < 4; i++) {
    int r = ty + i * 8;
    tile[r][tx] = f2b(in[(size_t)(r0 + r) * C + c0 + tx]);
  }
  __syncthreads();
#pragma unroll
  for (int i = 0; i < 4; i++) {
    int rr = ty + i * 8;
    out[(size_t)(c0 + rr) * R + r0 + tx] = tile[tx][rr];
  }
}

// ---------- GEMM1: drive = silu(u)*silu(v)+w, feats = x@W_in + b_in ----------
__global__ __launch_bounds__(256) void k_gemm_drive(const unsigned short* __restrict__ xb,
                                                    const unsigned short* __restrict__ WinT,
                                                    const float* __restrict__ b_in,
                                                    unsigned short* __restrict__ drive) {
  __shared__ unsigned short At[128 * 32];
  __shared__ unsigned short Bt[3][64 * 32];
  const int tid = threadIdx.x;
  const int w = tid >> 6, l = tid & 63;
  const int wm = w >> 1, wn = w & 1;
  const int lr = l & 15, lk = (l >> 4) * 8;
  const int m0 = blockIdx.x * 128;
  const int j0 = blockIdx.y * 64;
  f32x4 acc[3][4][2];
#pragma unroll
  for (int s = 0; s < 3; s++)
#pragma unroll
    for (int mi = 0; mi < 4; mi++)
#pragma unroll
      for (int ni = 0; ni < 2; ni++)
#pragma unroll
        for (int e = 0; e < 4; e++) acc[s][mi][ni][e] = 0.f;

  const int sr = tid >> 2;
  const int skb = (tid & 3) * 8;
  for (int kt = 0; kt < 32; kt++) {
    const int k0 = kt * 32;
    gload_lds16(xb + (size_t)(m0 + sr) * 1024 + k0 + skb, &At[w * 512]);
    gload_lds16(xb + (size_t)(m0 + 64 + sr) * 1024 + k0 + skb, &At[2048 + w * 512]);
#pragma unroll
    for (int s = 0; s < 3; s++)
      gload_lds16(WinT + (size_t)(s * 1024 + j0 + sr) * 1024 + k0 + skb, &Bt[s][w * 512]);
    __syncthreads();
    short8 Af[4], Bf[3][2];
#pragma unroll
    for (int mi = 0; mi < 4; mi++)
      Af[mi] = *(const short8*)&At[(wm * 64 + mi * 16 + lr) * 32 + lk];
#pragma unroll
    for (int s = 0; s < 3; s++)
#pragma unroll
      for (int ni = 0; ni < 2; ni++)
        Bf[s][ni] = *(const short8*)&Bt[s][(wn * 32 + ni * 16 + lr) * 32 + lk];
#pragma unroll
    for (int s = 0; s < 3; s++)
#pragma unroll
      for (int mi = 0; mi < 4; mi++)
#pragma unroll
        for (int ni = 0; ni < 2; ni++)
          acc[s][mi][ni] = mfma16(Af[mi], Bf[s][ni], acc[s][mi][ni]);
    __syncthreads();
  }
#pragma unroll
  for (int ni = 0; ni < 2; ni++) {
    const int c = j0 + wn * 32 + ni * 16 + lr;
    const float bu = b_in[c], bv = b_in[1024 + c], bw = b_in[2048 + c];
#pragma unroll
    for (int mi = 0; mi < 4; mi++) {
      const int r0 = m0 + wm * 64 + mi * 16 + (l >> 4) * 4;
#pragma unroll
      for (int e = 0; e < 4; e++) {
        float u = acc[0][mi][ni][e] + bu;
        float v = acc[1][mi][ni][e] + bv;
        float wv = acc[2][mi][ni][e] + bw;
        float su = u / (1.f + __expf(-u));
        float sv = v / (1.f + __expf(-v));
        drive[(size_t)(r0 + e) * 1024 + c] = f2b(su * sv + wv);
      }
    }
  }
}

// ---------- persistent scan kernel v4 ----------
// 64 WGs x 1024 threads (16 waves, 1 WG/CU). WG g owns h-features [16g,16g+16).
// Waves 0-11: MFMA role (mat = w>>2 in {gv,gt,rec}, kq = w&3 K-quarter).
//   Weight B-fragments (8 x short8 = 32 VGPR) loaded from global ONCE -> registers.
// Waves 12-15: pollers - tagged L3 exchange (hx word = (tag<<16)|bf16, tag=t),
//   pend-masked sweeps, pack validated words into XOR-swizzled LDS h-tile.
// Waves 0-1 (tid<128) double as finishers: K-quarter reduce from LDS buf, gate
//   math, tagged publish of h_{t+1}. Pollers poll t+1 concurrently with finish.
__global__ __launch_bounds__(1024, 4) void k_scan(const unsigned short* __restrict__ WgT,
                                                  const unsigned short* __restrict__ WrT,
                                                  const float* __restrict__ b_gate,
                                                  const float* __restrict__ b_rec,
                                                  const unsigned short* __restrict__ drive,
                                                  unsigned int* __restrict__ hx,
                                                  unsigned short* __restrict__ hs,
                                                  float* __restrict__ final_h) {
  const int g = blockIdx.x;           // 0..63
  const int tid = threadIdx.x;        // 0..1023
  const int w = tid >> 6, l = tid & 63;

  __shared__ unsigned short tile[8][1024];   // h_t (bf16), XOR-swizzled rows
  __shared__ float buf[4][8][48];            // per-K-quarter partial sums

  // ---- MFMA-wave setup (w<12): weights -> registers, 32 VGPR/wave ----
  const int mat = w >> 2, kq = w & 3;
  const int c = l & 15, ko = l >> 4;
  const bool av = c < 8;
  const unsigned swzA = (unsigned)((c & 7) << 4);
  short8 Breg[8];
  if (w < 12) {
    const unsigned short* WT = (mat == 2) ? WrT : WgT;
    const int rowbase = ((mat == 1) ? 1024 : 0) + g * 16;
#pragma unroll
    for (int ks = 0; ks < 8; ++ks)
      Breg[ks] = *(const short8*)&WT[(size_t)(rowbase + c) * 1024 +
                                     kq * 256 + ks * 32 + ko * 8];
  }

  // ---- poller setup (tid>=768) ----
  const bool isld = tid >= 768;
  const int L = tid & 255;
  const int lb = L >> 5, lc = L & 31;        // batch row, feature chunk
  char* ldsrow = (char*)&tile[0][0] + (size_t)(lb & 7) * 2048;
  const unsigned swzL = (unsigned)((lb & 7) << 4);

  // ---- finisher setup (tid<128) ----
  const bool isfin = tid < 128;
  const int fb = tid >> 4, ff = tid & 15;
  const int fcol = g * 16 + ff;
  float bgv = 0.f, bgt = 0.f, brc = 0.f;
  if (isfin) { bgv = b_gate[fcol]; bgt = b_gate[1024 + fcol]; brc = b_rec[fcol]; }

  for (int t = 0; t < 2048; ++t) {
    const int p = t & 1;
    unsigned short dpf = 0;
    if (isfin) dpf = drive[(size_t)(fb * 2048 + t) * 1024 + fcol];

    if (isld) {  // ---- poll h_t (tags == t), pack validated words to tile ----
      const unsigned tg = (unsigned)t;
      const u64* hb = (const u64*)(hx + (size_t)p * 8192) + (lb * 512 + lc);
      unsigned pend = 0xffffu;
      do {
        u64 v[16];
#pragma unroll
        for (int q = 0; q < 16; ++q)
          if ((pend >> q) & 1)
            v[q] = __hip_atomic_load(hb + q * 32, __ATOMIC_RELAXED,
                                     __HIP_MEMORY_SCOPE_AGENT);
        unsigned np = 0;
#pragma unroll
        for (int q = 0; q < 16; ++q)
          if ((pend >> q) & 1) {
            unsigned lo = (unsigned)v[q], hi = (unsigned)(v[q] >> 32);
            if (((lo >> 16) == tg) & ((hi >> 16) == tg)) {
              unsigned pk = __builtin_amdgcn_perm(hi, lo, 0x05040100u);
              *(unsigned*)(ldsrow + (((unsigned)(q * 128 + lc * 4)) ^ swzL)) = pk;
            } else np |= 1u << q;
          }
        pend = np;
      } while (pend);
    }
    __syncthreads();   // tile(t) complete

    // ---- MFMA: 8 k-slices per wave, 2 independent chains ----
    if (w < 12) {
      const char* base = (const char*)&tile[0][0] + (size_t)c * 2048;
      f32x4 a0, a1;
#pragma unroll
      for (int e = 0; e < 4; ++e) { a0[e] = 0.f; a1[e] = 0.f; }
#pragma unroll
      for (int ks = 0; ks < 8; ++ks) {
        const unsigned off = ((unsigned)(kq * 512 + ks * 64 + ko * 16)) ^ swzA;
        short8 Af;
#pragma unroll
        for (int e = 0; e < 8; ++e) Af[e] = 0;
        if (av) Af = *(const short8*)(base + off);
        if (ks & 1) a1 = mfma16(Af, Breg[ks], a1);
        else        a0 = mfma16(Af, Breg[ks], a0);
      }
      if (l < 32) {
        const int r0 = ko * 4;     // ko in {0,1} for l<32 -> batches 0..7
#pragma unroll
        for (int e = 0; e < 4; ++e)
          buf[kq][r0 + e][mat * 16 + c] = a0[e] + a1[e];
      }
    }
    __syncthreads();   // buf complete; tile free for t+1

    // ---- finisher: K-quarter reduce + gate math + tagged publish ----
    if (isfin) {
      const float gv = ((buf[0][fb][ff] + buf[1][fb][ff]) +
                        (buf[2][fb][ff] + buf[3][fb][ff])) + bgv;
      const float gt = ((buf[0][fb][16 + ff] + buf[1][fb][16 + ff]) +
                        (buf[2][fb][16 + ff] + buf[3][fb][16 + ff])) + bgt;
      const float rc = ((buf[0][fb][32 + ff] + buf[1][fb][32 + ff]) +
                        (buf[2][fb][32 + ff] + buf[3][fb][32 + ff])) + brc;
      const float sgv = 1.f / (1.f + __expf(-gv));
      const float sgt = 1.f / (1.f + __expf(-gt));
      const float gate = sgv * gt * sgt;  // sigmoid(gv) * silu(gt)
      const float nh = gate * rc + (1.f - gate) * b2f(dpf);
      const unsigned short nhb = f2b(nh);
      __hip_atomic_store(hx + (size_t)(p ^ 1) * 8192 + fb * 1024 + fcol,
                         (((unsigned)(t + 1)) << 16) | (unsigned)nhb,
                         __ATOMIC_RELAXED, __HIP_MEMORY_SCOPE_AGENT);
      hs[(size_t)(fb * 2048 + t) * 1024 + fcol] = nhb;
      if (t == 2047) final_h[fb * 1024 + fcol] = nh;
    }
  }
}

// ---------- GEMM3: out = hs @ W_out + b_out ----------
__global__ __launch_bounds__(256) void k_gemm_out(const unsigned short* __restrict__ hs,
                                                  const unsigned short* __restrict__ WoT,
                                                  const float* __restrict__ b_out,
                                                  float* __restrict__ out) {
  __shared__ unsigned short At[128 * 32];
  __shared__ unsigned short Bt[128 * 32];
  const int tid = threadIdx.x;
  const int w = tid >> 6, l = tid & 63;
  const int wm = w >> 1, wn = w & 1;
  const int lr = l & 15, lk = (l >> 4) * 8;
  const int m0 = blockIdx.x * 128;
  const int n0 = blockIdx.y * 128;
  f32x4 acc[4][4];
#pragma unroll
  for (int mi = 0; mi < 4; mi++)
#pragma unroll
    for (int ni = 0; ni < 4; ni++)
#pragma unroll
      for (int e = 0; e < 4; e++) acc[mi][ni][e] = 0.f;

  const int sr = tid >> 2;
  const int skb = (tid & 3) * 8;
  for (int kt = 0; kt < 32; kt++) {
    const int k0 = kt * 32;
    gload_lds16(hs + (size_t)(m0 + sr) * 1024 + k0 + skb, &At[w * 512]);
    gload_lds16(hs + (size_t)(m0 + 64 + sr) * 1024 + k0 + skb, &At[2048 + w * 512]);
    gload_lds16(WoT + (size_t)(n0 + sr) * 1024 + k0 + skb, &Bt[w * 512]);
    gload_lds16(WoT + (size_t)(n0 + 64 + sr) * 1024 + k0 + skb, &Bt[2048 + w * 512]);
    __syncthreads();
    short8 Af[4], Bf[4];
#pragma unroll
    for (int mi = 0; mi < 4; mi++)
      Af[mi] = *(const short8*)&At[(wm * 64 + mi * 16 + lr) * 32 + lk];
#pragma unroll
    for (int ni = 0; ni < 4; ni++)
      Bf[ni] = *(const short8*)&Bt[(wn * 64 + ni * 16 + lr) * 32 + lk];
#pragma unroll
    for (int mi = 0; mi < 4; mi++)
#pragma unroll
      for (int ni = 0; ni < 4; ni++)
        acc[mi][ni] = mfma16(Af[mi], Bf[ni], acc[mi][ni]);
    __syncthreads();
  }
#pragma unroll
  for (int ni = 0; ni < 4; ni++) {
    const int c = n0 + wn * 64 + ni * 16 + lr;
    const float bo = b_out[c];
#pragma unroll
    for (int mi = 0; mi < 4; mi++) {
      const int r0 = m0 + wm * 64 + mi * 16 + (l >> 4) * 4;
#pragma unroll
      for (int e = 0; e < 4; e++)
        out[(size_t)(r0 + e) * 1024 + c] = acc[mi][ni][e] + bo;
    }
  }
}

// ---------- launch ----------
extern "C" void kernel_launch(void* const* d_in, const int* in_sizes, int n_in,
                              void* d_out, int out_size, void* d_ws, size_t ws_size,
                              hipStream_t stream) {
  const float* x      = (const float*)d_in[0];
  const float* h0     = (const float*)d_in[1];
  const float* W_in   = (const float*)d_in[2];
  const float* b_in   = (const float*)d_in[3];
  const float* W_gate = (const float*)d_in[4];
  const float* b_gate = (const float*)d_in[5];
  const float* W_rec  = (const float*)d_in[6];
  const float* b_rec  = (const float*)d_in[7];
  const float* W_out  = (const float*)d_in[8];
  const float* b_out  = (const float*)d_in[9];
  float* outp = (float*)d_out;

  size_t off = 0;
  auto alloc = [&](size_t bytes) {
    void* p = (char*)d_ws + off;
    off += (bytes + 255) & ~(size_t)255;
    return p;
  };
  unsigned short* xb    = (unsigned short*)alloc((size_t)16777216 * 2);
  unsigned short* WinT  = (unsigned short*)alloc((size_t)3072 * 1024 * 2);
  unsigned short* WgT   = (unsigned short*)alloc((size_t)2048 * 1024 * 2);
  unsigned short* WrT   = (unsigned short*)alloc((size_t)1024 * 1024 * 2);
  unsigned short* WoT   = (unsigned short*)alloc((size_t)1024 * 1024 * 2);
  unsigned short* drive = (unsigned short*)alloc((size_t)16777216 * 2);
  unsigned short* hs    = (unsigned short*)alloc((size_t)16777216 * 2);
  unsigned int*   hx    = (unsigned int*)alloc((size_t)2 * 8192 * 4);

  // conversions / init
  k_cvt_bf16<<<16384, 256, 0, stream>>>(x, xb, 4194304);
  k_transpose_bf16<<<dim3(96, 32), 256, 0, stream>>>(W_in, WinT, 1024, 3072);
  k_transpose_bf16<<<dim3(64, 32), 256, 0, stream>>>(W_gate, WgT, 1024, 2048);
  k_transpose_bf16<<<dim3(32, 32), 256, 0, stream>>>(W_rec, WrT, 1024, 1024);
  k_transpose_bf16<<<dim3(32, 32), 256, 0, stream>>>(W_out, WoT, 1024, 1024);
  k_init_hx<<<32, 256, 0, stream>>>(h0, hx);

  // drive = silu(u)*silu(v)+w
  k_gemm_drive<<<dim3(128, 16), 256, 0, stream>>>(xb, WinT, b_in, drive);
  // sequential recurrence (persistent kernel, 64 WGs x 16 waves, reg weights)
  k_scan<<<64, 1024, 0, stream>>>(WgT, WrT, b_gate, b_rec, drive, hx, hs,
                                  outp + 16777216);
  // out = hs @ W_out + b_out
  k_gemm_out<<<dim3(128, 8), 256, 0, stream>>>(hs, WoT, b_out, outp);
}